// Round 2
// baseline (394.004 us; speedup 1.0000x reference)
//
#include <hip/hip_runtime.h>

#define BB   16
#define C0   1024
#define C1   512
#define LEN  2048
#define BC   256
#define RC   64
#define NB0  4
#define NB1  2
#define KK   6
#define EPSV 1e-5f

typedef float vfloat4 __attribute__((ext_vector_type(4)));

// ---------------- Kernel 1: global-average-pool over blocks+L ----------------
// One block per (b, c). Sums 6 rows of 2048 floats, writes gap[b*BC+c] = sum/L.
// Normal (caching) loads on purpose: this pass warms x into L3 for kernel 3.
__global__ __launch_bounds__(256) void gap_kernel(const float* __restrict__ x0,
                                                  const float* __restrict__ x1,
                                                  float* __restrict__ gap) {
    const int c = blockIdx.x;   // 0..255
    const int b = blockIdx.y;   // 0..15
    const int t = threadIdx.x;  // 0..255

    const vfloat4* rows[KK];
#pragma unroll
    for (int k = 0; k < NB0; ++k)
        rows[k] = (const vfloat4*)(x0 + ((size_t)b * C0 + (size_t)k * BC + c) * LEN);
#pragma unroll
    for (int k = 0; k < NB1; ++k)
        rows[NB0 + k] = (const vfloat4*)(x1 + ((size_t)b * C1 + (size_t)k * BC + c) * LEN);

    float s = 0.f;
#pragma unroll
    for (int k = 0; k < KK; ++k) {
        vfloat4 v0 = rows[k][t];
        vfloat4 v1 = rows[k][t + 256];
        s += (v0.x + v0.y) + (v0.z + v0.w) + (v1.x + v1.y) + (v1.z + v1.w);
    }
#pragma unroll
    for (int off = 32; off > 0; off >>= 1)
        s += __shfl_down(s, off, 64);
    __shared__ float ws_[4];
    if ((t & 63) == 0) ws_[t >> 6] = s;
    __syncthreads();
    if (t == 0) {
        float tot = (ws_[0] + ws_[1]) + (ws_[2] + ws_[3]);
        gap[b * BC + c] = tot * (1.0f / (float)LEN);
    }
}

// ------------- Kernel 2: joint linear + BN + ReLU, grouped linear, softmax ---
// One block per batch b, 1024 threads (16 waves). The 384KB cold Wg read is
// the latency bottleneck: each thread PRELOADS its first (k,c) Wg row into
// registers (16 x vfloat4) BEFORE the h-GEMV, so the cold HBM latency hides
// under the gap-load + Wj reduce. Second 512 pairs use vectorized loads.
__global__ __launch_bounds__(1024) void atten_kernel(const float* __restrict__ gap,
                                                     const float* __restrict__ Wj,   // [RC,BC]
                                                     const float* __restrict__ bj,   // [RC]
                                                     const float* __restrict__ gamma,
                                                     const float* __restrict__ beta,
                                                     const float* __restrict__ mean,
                                                     const float* __restrict__ var,
                                                     const float* __restrict__ Wg,   // [KK,BC,RC]
                                                     const float* __restrict__ bg,   // [KK,BC]
                                                     float* __restrict__ atten) {    // [KK,BB,BC]
    const int b    = blockIdx.x;
    const int t    = threadIdx.x;   // 0..1023
    const int lane = t & 63;
    const int wave = t >> 6;        // 0..15
    __shared__ float g_s[BC];
    __shared__ float h_s[RC];
    __shared__ float l_s[KK][BC];

    // ---- issue pair-1 Wg loads early (independent of gap/h) ----
    const int k1 = t >> 8, c1 = t & 255;          // pair index t (0..1023 < 1536)
    const vfloat4* w1 = (const vfloat4*)(Wg + ((size_t)k1 * BC + c1) * RC);
    vfloat4 wreg[16];
#pragma unroll
    for (int i = 0; i < 16; ++i) wreg[i] = w1[i];
    const float bias1 = bg[k1 * BC + c1];

    if (t < BC) g_s[t] = gap[b * BC + t];
    __syncthreads();

    // h[r] for r = wave*4 .. wave*4+3 : coalesced Wj row loads + wave reduce
#pragma unroll
    for (int i = 0; i < 4; ++i) {
        const int r = wave * 4 + i;
        const float* w = Wj + (size_t)r * BC;
        float acc = fmaf(w[lane], g_s[lane],
                    fmaf(w[lane + 64], g_s[lane + 64],
                    fmaf(w[lane + 128], g_s[lane + 128],
                         w[lane + 192] * g_s[lane + 192])));
#pragma unroll
        for (int off = 32; off > 0; off >>= 1)
            acc += __shfl_down(acc, off, 64);
        if (lane == 0) {
            float v = acc + bj[r];
            v = (v - mean[r]) * rsqrtf(var[r] + EPSV) * gamma[r] + beta[r];
            h_s[r] = fmaxf(v, 0.f);
        }
    }
    __syncthreads();

    // pair-1 logits: Wg already in registers
    {
        float acc = bias1;
#pragma unroll
        for (int i = 0; i < 16; ++i) {
            acc = fmaf(h_s[4 * i + 0], wreg[i].x, acc);
            acc = fmaf(h_s[4 * i + 1], wreg[i].y, acc);
            acc = fmaf(h_s[4 * i + 2], wreg[i].z, acc);
            acc = fmaf(h_s[4 * i + 3], wreg[i].w, acc);
        }
        l_s[k1][c1] = acc;
    }
    // pair-2: 512 remaining (k,c) pairs on threads 0..511, vectorized loads
    const int t2 = t + 1024;
    if (t2 < KK * BC) {
        const int k = t2 >> 8, c = t2 & 255;
        const vfloat4* w = (const vfloat4*)(Wg + ((size_t)k * BC + c) * RC);
        float acc = bg[k * BC + c];
#pragma unroll
        for (int i = 0; i < 16; ++i) {
            vfloat4 v = w[i];
            acc = fmaf(h_s[4 * i + 0], v.x, acc);
            acc = fmaf(h_s[4 * i + 1], v.y, acc);
            acc = fmaf(h_s[4 * i + 2], v.z, acc);
            acc = fmaf(h_s[4 * i + 3], v.w, acc);
        }
        l_s[k][c] = acc;
    }
    __syncthreads();

    if (t < BC) {
        float logit[KK];
#pragma unroll
        for (int k = 0; k < KK; ++k) logit[k] = l_s[k][t];
        float m = logit[0];
#pragma unroll
        for (int k = 1; k < KK; ++k) m = fmaxf(m, logit[k]);
        float sum = 0.f;
#pragma unroll
        for (int k = 0; k < KK; ++k) { logit[k] = __expf(logit[k] - m); sum += logit[k]; }
        const float inv = 1.f / sum;
#pragma unroll
        for (int k = 0; k < KK; ++k)
            atten[((size_t)k * BB + b) * BC + t] = logit[k] * inv;
    }
}

// ---------------- Kernel 3: broadcast scale -> out0 | out1 -------------------
// 4 channel-rows per block (32KB moved per block vs 8KB before): 4x fewer
// workgroup dispatches, 4 independent row-streams per block for latency hiding.
// x loads are normal (hit L3, warmed by K1); out stores NON-TEMPORAL so the
// 192MB output stream doesn't evict x.
__global__ __launch_bounds__(256) void scale_kernel(const float* __restrict__ x0,
                                                    const float* __restrict__ x1,
                                                    const float* __restrict__ atten,
                                                    float* __restrict__ out) {
    const int t    = threadIdx.x;
    const int row0 = blockIdx.x * 4;       // 0..24572
#pragma unroll
    for (int j = 0; j < 4; ++j) {
        const int row = row0 + j;
        const int b  = row / (C0 + C1);
        const int ch = row - b * (C0 + C1);

        const vfloat4* src;
        vfloat4* dst;
        float scale;
        if (ch < C0) {
            const int k = ch >> 8, c = ch & 255;
            scale = atten[((size_t)k * BB + b) * BC + c];
            src = (const vfloat4*)(x0 + ((size_t)b * C0 + ch) * LEN);
            dst = (vfloat4*)(out + ((size_t)b * C0 + ch) * LEN);
        } else {
            const int ch1 = ch - C0;
            const int k = NB0 + (ch1 >> 8), c = ch1 & 255;
            scale = atten[((size_t)k * BB + b) * BC + c];
            src = (const vfloat4*)(x1 + ((size_t)b * C1 + ch1) * LEN);
            dst = (vfloat4*)(out + (size_t)BB * C0 * LEN + ((size_t)b * C1 + ch1) * LEN);
        }
        vfloat4 v0 = src[t];
        vfloat4 v1 = src[t + 256];
        v0 *= scale;
        v1 *= scale;
        __builtin_nontemporal_store(v0, &dst[t]);
        __builtin_nontemporal_store(v1, &dst[t + 256]);
    }
}

extern "C" void kernel_launch(void* const* d_in, const int* in_sizes, int n_in,
                              void* d_out, int out_size, void* d_ws, size_t ws_size,
                              hipStream_t stream) {
    const float* x0    = (const float*)d_in[0];
    const float* x1    = (const float*)d_in[1];
    const float* Wj    = (const float*)d_in[2];
    const float* bj    = (const float*)d_in[3];
    const float* gamma = (const float*)d_in[4];
    const float* beta  = (const float*)d_in[5];
    const float* mean  = (const float*)d_in[6];
    const float* var   = (const float*)d_in[7];
    const float* Wg    = (const float*)d_in[8];
    const float* bg    = (const float*)d_in[9];
    float* out = (float*)d_out;

    float* ws    = (float*)d_ws;
    float* gap   = ws;          // BB*BC    = 4096 floats
    float* atten = ws + 4096;   // KK*BB*BC = 24576 floats

    gap_kernel<<<dim3(BC, BB), 256, 0, stream>>>(x0, x1, gap);
    atten_kernel<<<BB, 1024, 0, stream>>>(gap, Wj, bj, gamma, beta, mean, var, Wg, bg, atten);
    scale_kernel<<<(BB * (C0 + C1)) / 4, 256, 0, stream>>>(x0, x1, atten, out);
}

// Round 3
// 383.849 us; speedup vs baseline: 1.0265x; 1.0265x over previous
//
#include <hip/hip_runtime.h>

#define BB   16
#define C0   1024
#define C1   512
#define LEN  2048
#define BC   256
#define RC   64
#define NB0  4
#define NB1  2
#define KK   6
#define EPSV 1e-5f

typedef float vfloat4 __attribute__((ext_vector_type(4)));

// ---------------- Kernel 1: global-average-pool over blocks+L ----------------
// One block per (b, c). Sums 6 rows of 2048 floats, writes gap[b*BC+c] = sum/L.
// Normal (caching) loads on purpose: this pass warms x into L3 for kernel 2.
__global__ __launch_bounds__(256) void gap_kernel(const float* __restrict__ x0,
                                                  const float* __restrict__ x1,
                                                  float* __restrict__ gap) {
    const int c = blockIdx.x;   // 0..255
    const int b = blockIdx.y;   // 0..15
    const int t = threadIdx.x;  // 0..255

    const vfloat4* rows[KK];
#pragma unroll
    for (int k = 0; k < NB0; ++k)
        rows[k] = (const vfloat4*)(x0 + ((size_t)b * C0 + (size_t)k * BC + c) * LEN);
#pragma unroll
    for (int k = 0; k < NB1; ++k)
        rows[NB0 + k] = (const vfloat4*)(x1 + ((size_t)b * C1 + (size_t)k * BC + c) * LEN);

    float s = 0.f;
#pragma unroll
    for (int k = 0; k < KK; ++k) {
        vfloat4 v0 = rows[k][t];
        vfloat4 v1 = rows[k][t + 256];
        s += (v0.x + v0.y) + (v0.z + v0.w) + (v1.x + v1.y) + (v1.z + v1.w);
    }
#pragma unroll
    for (int off = 32; off > 0; off >>= 1)
        s += __shfl_down(s, off, 64);
    __shared__ float ws_[4];
    if ((t & 63) == 0) ws_[t >> 6] = s;
    __syncthreads();
    if (t == 0) {
        float tot = (ws_[0] + ws_[1]) + (ws_[2] + ws_[3]);
        gap[b * BC + c] = tot * (1.0f / (float)LEN);
    }
}

// --------- Kernel 2: fused {joint MLP + grouped logits + softmax + scale} ----
// One block per (b, c) pair, handling all 6 k-rows (same 48 KiB footprint as
// gap_kernel, so x reads hit the L3 lines K1 warmed). x is prefetched into
// registers BEFORE the attention math so streaming starts immediately.
// h[64] is computed redundantly per block (Wj is 64 KiB, L2-resident; 256 MiB
// aggregate ~ 6% of L2 BW) -- this removes the separate atten dispatch.
__global__ __launch_bounds__(256) void atten_scale_kernel(
    const float* __restrict__ x0, const float* __restrict__ x1,
    const float* __restrict__ gap,
    const float* __restrict__ Wj,   // [RC,BC]
    const float* __restrict__ bj,   // [RC]
    const float* __restrict__ gamma,
    const float* __restrict__ beta,
    const float* __restrict__ mean,
    const float* __restrict__ var,
    const float* __restrict__ Wg,   // [KK,BC,RC]
    const float* __restrict__ bg,   // [KK,BC]
    float* __restrict__ out)
{
    const int c    = blockIdx.x;   // 0..255
    const int b    = blockIdx.y;   // 0..15
    const int t    = threadIdx.x;  // 0..255
    const int lane = t & 63;
    const int wave = t >> 6;       // 0..3

    __shared__ float h_s[RC];

    // ---- prefetch the 6 x rows into registers (independent of atten math) ----
    const float* xbase0 = x0 + ((size_t)b * C0 + c) * LEN;
    const float* xbase1 = x1 + ((size_t)b * C1 + c) * LEN;
    vfloat4 va[KK], vb[KK];
#pragma unroll
    for (int k = 0; k < NB0; ++k) {
        const vfloat4* r = (const vfloat4*)(xbase0 + (size_t)k * BC * LEN);
        va[k] = r[t];
        vb[k] = r[t + 256];
    }
#pragma unroll
    for (int k = 0; k < NB1; ++k) {
        const vfloat4* r = (const vfloat4*)(xbase1 + (size_t)k * BC * LEN);
        va[NB0 + k] = r[t];
        vb[NB0 + k] = r[t + 256];
    }

    // ---- h (raw joint-linear): 4 waves x 16 rows, vectorized Wj row loads ----
    const vfloat4* gv  = (const vfloat4*)(gap + (size_t)b * BC);
    const vfloat4  g4  = gv[lane];                  // gap[b, 4*lane .. 4*lane+3]
    const vfloat4* Wjv = (const vfloat4*)Wj;
#pragma unroll
    for (int i = 0; i < 16; ++i) {
        const int r = wave * 16 + i;
        vfloat4 w4 = Wjv[(size_t)r * 64 + lane];    // full 1KiB row per wave-inst
        float acc = fmaf(w4.x, g4.x, fmaf(w4.y, g4.y, fmaf(w4.z, g4.z, w4.w * g4.w)));
#pragma unroll
        for (int off = 32; off > 0; off >>= 1)
            acc += __shfl_down(acc, off, 64);
        if (lane == 0) h_s[r] = acc;                // raw; BN applied per-lane later
    }
    __syncthreads();

    // ---- BN + ReLU per-lane (coalesced param loads, once per thread) ----
    float hr;
    {
        float v = h_s[lane] + bj[lane];
        v = (v - mean[lane]) * rsqrtf(var[lane] + EPSV) * gamma[lane] + beta[lane];
        hr = fmaxf(v, 0.f);                         // lane holds h[lane]
    }

    // ---- 6 logits: lane-parallel dot + butterfly (all lanes get the sum) ----
    float lg[KK];
#pragma unroll
    for (int k = 0; k < KK; ++k) {
        const float* w = Wg + ((size_t)k * BC + c) * RC;
        float p = hr * w[lane];
#pragma unroll
        for (int off = 32; off > 0; off >>= 1)
            p += __shfl_xor(p, off, 64);
        lg[k] = p + bg[k * BC + c];
    }

    // ---- softmax over k (redundant per thread, all identical) ----
    float m = lg[0];
#pragma unroll
    for (int k = 1; k < KK; ++k) m = fmaxf(m, lg[k]);
    float sum = 0.f;
#pragma unroll
    for (int k = 0; k < KK; ++k) { lg[k] = __expf(lg[k] - m); sum += lg[k]; }
    const float inv = 1.f / sum;

    // ---- scale the prefetched registers, non-temporal store ----
    float* obase0 = out + ((size_t)b * C0 + c) * LEN;
    float* obase1 = out + (size_t)BB * C0 * LEN + ((size_t)b * C1 + c) * LEN;
#pragma unroll
    for (int k = 0; k < NB0; ++k) {
        const float s = lg[k] * inv;
        vfloat4* d = (vfloat4*)(obase0 + (size_t)k * BC * LEN);
        vfloat4 o0 = va[k] * s;
        vfloat4 o1 = vb[k] * s;
        __builtin_nontemporal_store(o0, &d[t]);
        __builtin_nontemporal_store(o1, &d[t + 256]);
    }
#pragma unroll
    for (int k = 0; k < NB1; ++k) {
        const float s = lg[NB0 + k] * inv;
        vfloat4* d = (vfloat4*)(obase1 + (size_t)k * BC * LEN);
        vfloat4 o0 = va[NB0 + k] * s;
        vfloat4 o1 = vb[NB0 + k] * s;
        __builtin_nontemporal_store(o0, &d[t]);
        __builtin_nontemporal_store(o1, &d[t + 256]);
    }
}

extern "C" void kernel_launch(void* const* d_in, const int* in_sizes, int n_in,
                              void* d_out, int out_size, void* d_ws, size_t ws_size,
                              hipStream_t stream) {
    const float* x0    = (const float*)d_in[0];
    const float* x1    = (const float*)d_in[1];
    const float* Wj    = (const float*)d_in[2];
    const float* bj    = (const float*)d_in[3];
    const float* gamma = (const float*)d_in[4];
    const float* beta  = (const float*)d_in[5];
    const float* mean  = (const float*)d_in[6];
    const float* var   = (const float*)d_in[7];
    const float* Wg    = (const float*)d_in[8];
    const float* bg    = (const float*)d_in[9];
    float* out = (float*)d_out;

    float* gap = (float*)d_ws;   // BB*BC = 4096 floats

    gap_kernel<<<dim3(BC, BB), 256, 0, stream>>>(x0, x1, gap);
    atten_scale_kernel<<<dim3(BC, BB), 256, 0, stream>>>(
        x0, x1, gap, Wj, bj, gamma, beta, mean, var, Wg, bg, out);
}